// Round 1
// baseline (24679.950 us; speedup 1.0000x reference)
//
#include <hip/hip_runtime.h>
#include <math.h>

#define TT  512   // timesteps
#define BB  64    // batch
#define EMBD 512
#define HIDD 512

// ---------------------------------------------------------------------------
// K1: px[m][j] = b1[j] + sum_k emb[x[m]][k] * W1[j][k]   (m = b*T+t, k<512)
// fp32 128x128x8 tile GEMM, 256 threads, 8x8 per thread.
// ---------------------------------------------------------------------------
__global__ __launch_bounds__(256) void px_gemm(
    const int* __restrict__ x, const float* __restrict__ emb,
    const float* __restrict__ W1, const float* __restrict__ b1,
    float* __restrict__ px)
{
  __shared__ float As[8][132];
  __shared__ float Bs[8][132];
  __shared__ int stok[128];
  const int tid = threadIdx.x;
  const int m0 = blockIdx.x * 128;
  const int j0 = blockIdx.y * 128;
  if (tid < 128) stok[tid] = x[m0 + tid];
  __syncthreads();
  const int lr = tid >> 1;          // 0..127
  const int lh = (tid & 1) * 4;     // 0 or 4
  const int ty = tid >> 4, tx = tid & 15;
  const size_t arow = (size_t)stok[lr] * EMBD;
  const float* brow = W1 + (size_t)(j0 + lr) * (2 * EMBD);

  float acc[8][8];
#pragma unroll
  for (int i = 0; i < 8; i++)
#pragma unroll
    for (int q = 0; q < 8; q++) acc[i][q] = 0.f;

  for (int k0 = 0; k0 < EMBD; k0 += 8) {
    float4 av = *(const float4*)(emb + arow + k0 + lh);
    float4 bv = *(const float4*)(brow + k0 + lh);
    __syncthreads();
    As[lh + 0][lr] = av.x; As[lh + 1][lr] = av.y; As[lh + 2][lr] = av.z; As[lh + 3][lr] = av.w;
    Bs[lh + 0][lr] = bv.x; Bs[lh + 1][lr] = bv.y; Bs[lh + 2][lr] = bv.z; Bs[lh + 3][lr] = bv.w;
    __syncthreads();
#pragma unroll
    for (int kk = 0; kk < 8; kk++) {
      float4 a0 = *(const float4*)&As[kk][ty * 8];
      float4 a1 = *(const float4*)&As[kk][ty * 8 + 4];
      float4 c0 = *(const float4*)&Bs[kk][tx * 8];
      float4 c1 = *(const float4*)&Bs[kk][tx * 8 + 4];
      float a[8] = {a0.x,a0.y,a0.z,a0.w,a1.x,a1.y,a1.z,a1.w};
      float bb[8] = {c0.x,c0.y,c0.z,c0.w,c1.x,c1.y,c1.z,c1.w};
#pragma unroll
      for (int i = 0; i < 8; i++)
#pragma unroll
        for (int q = 0; q < 8; q++)
          acc[i][q] = fmaf(a[i], bb[q], acc[i][q]);
    }
  }
  const float* bp = b1 + j0 + tx * 8;
  float bias0[8];
#pragma unroll
  for (int q = 0; q < 8; q++) bias0[q] = bp[q];
#pragma unroll
  for (int i = 0; i < 8; i++) {
    float o[8];
#pragma unroll
    for (int q = 0; q < 8; q++) o[q] = acc[i][q] + bias0[q];
    float* dst = px + (size_t)(m0 + ty * 8 + i) * HIDD + j0 + tx * 8;
    *(float4*)dst       = make_float4(o[0], o[1], o[2], o[3]);
    *(float4*)(dst + 4) = make_float4(o[4], o[5], o[6], o[7]);
  }
}

// ---------------------------------------------------------------------------
// K2: persistent recurrence. 256 wgs = 64 batches x 4 output-slices.
// Each thread holds 128 W1h weights in VGPRs. Per step: stage h (LDS),
// partial dot, 4-way LDS reduce, tanh, publish slice, 4-wg flag sync.
// ---------------------------------------------------------------------------
template<bool HAS_PX>
__global__ __launch_bounds__(512, 2) void elman_rnn(
    const float* __restrict__ W1, const float* __restrict__ b1,
    const float* __restrict__ W2, const float* __restrict__ b2,
    const float* __restrict__ emb, const int* __restrict__ x,
    const float* __restrict__ px, float* __restrict__ hbufs,
    float* __restrict__ pooled, int* __restrict__ flags,
    float* __restrict__ out)
{
  const int blk = blockIdx.x;
  const int b = blk & 63;      // batch
  const int s = blk >> 6;      // output slice 0..3 (same-XCD grouping per batch)
  const int tid = threadIdx.x;
  const int kc = tid >> 7;     // k-chunk 0..3 (wave-uniform)
  const int jl = tid & 127;    // output within slice
  const int j = s * 128 + jl;

  __shared__ float hl[HIDD];
  __shared__ float el[EMBD];
  __shared__ float parts[4][128];
  __shared__ float red[2][8];

  float4 w[32];
  {
    const float4* wp = (const float4*)(W1 + (size_t)j * (2 * EMBD) + EMBD + kc * 128);
#pragma unroll
    for (int i = 0; i < 32; i++) w[i] = wp[i];
  }
  float bias = 0.f;
  if (!HAS_PX && tid < 128) bias = b1[s * 128 + tid];
  float runmax = -INFINITY;
  int* flg = flags + b;

  for (int t = 0; t < TT; t++) {
    float pxv = 0.f;
    if constexpr (HAS_PX) {
      if (tid < 128) pxv = px[((size_t)b * TT + t) * HIDD + s * 128 + tid];
    }
    float hval = 0.f;
    if (t > 0) {
      const float* hr = hbufs + (size_t)(t & 1) * (BB * HIDD) + b * HIDD;
      hval = __hip_atomic_load(hr + tid, __ATOMIC_RELAXED, __HIP_MEMORY_SCOPE_AGENT);
    }
    int tk = 0;
    if constexpr (!HAS_PX) tk = x[b * TT + t];
    __syncthreads();                    // LDS reuse guard
    hl[tid] = hval;
    if constexpr (!HAS_PX) el[tid] = emb[(size_t)tk * EMBD + tid];
    __syncthreads();

    float partial = 0.f;
    const float4* h4 = (const float4*)(hl + kc * 128);
#pragma unroll
    for (int i = 0; i < 32; i++) {
      float4 hv = h4[i];
      partial = fmaf(w[i].x, hv.x, partial);
      partial = fmaf(w[i].y, hv.y, partial);
      partial = fmaf(w[i].z, hv.z, partial);
      partial = fmaf(w[i].w, hv.w, partial);
    }
    if constexpr (!HAS_PX) {
      const float4* wx = (const float4*)(W1 + (size_t)j * (2 * EMBD) + kc * 128);
      const float4* e4 = (const float4*)(el + kc * 128);
#pragma unroll
      for (int i = 0; i < 32; i++) {
        float4 a = wx[i]; float4 e = e4[i];
        partial = fmaf(a.x, e.x, partial);
        partial = fmaf(a.y, e.y, partial);
        partial = fmaf(a.z, e.z, partial);
        partial = fmaf(a.w, e.w, partial);
      }
    }
    parts[kc][jl] = partial;
    __syncthreads();
    if (tid < 128) {
      float pre = parts[0][tid] + parts[1][tid] + parts[2][tid] + parts[3][tid] + pxv + bias;
      float hn = tanhf(pre);
      runmax = fmaxf(runmax, hn);
      float* hw = hbufs + (size_t)((t + 1) & 1) * (BB * HIDD) + b * HIDD + s * 128 + tid;
      __hip_atomic_store(hw, hn, __ATOMIC_RELAXED, __HIP_MEMORY_SCOPE_AGENT);
      if (t == TT - 1) out[2 * BB + (size_t)b * HIDD + s * 128 + tid] = hn;
    }
    __syncthreads();                    // all slice stores reached L2 (vmcnt drained)
    if (tid == 0) __hip_atomic_fetch_add(flg, 1, __ATOMIC_RELEASE, __HIP_MEMORY_SCOPE_AGENT);
    const int target = 4 * (t + 1);
    int guard = 0;
    while (__hip_atomic_load(flg, __ATOMIC_ACQUIRE, __HIP_MEMORY_SCOPE_AGENT) < target) {
      __builtin_amdgcn_s_sleep(1);
      if (++guard > (1 << 22)) break;   // safety: never hang the harness
    }
  }

  // ---- pooled max -> logits ----
  if (tid < 128)
    __hip_atomic_store(pooled + b * HIDD + s * 128 + tid, runmax,
                       __ATOMIC_RELAXED, __HIP_MEMORY_SCOPE_AGENT);
  __syncthreads();
  if (tid == 0) __hip_atomic_fetch_add(flg, 1, __ATOMIC_RELEASE, __HIP_MEMORY_SCOPE_AGENT);
  if (s == 0) {
    const int target = 4 * TT + 4;
    int guard = 0;
    while (__hip_atomic_load(flg, __ATOMIC_ACQUIRE, __HIP_MEMORY_SCOPE_AGENT) < target) {
      __builtin_amdgcn_s_sleep(1);
      if (++guard > (1 << 22)) break;
    }
    float pv = __hip_atomic_load(pooled + b * HIDD + tid, __ATOMIC_RELAXED, __HIP_MEMORY_SCOPE_AGENT);
    float p0 = pv * W2[tid];
    float p1 = pv * W2[HIDD + tid];
#pragma unroll
    for (int off = 32; off; off >>= 1) {
      p0 += __shfl_down(p0, off);
      p1 += __shfl_down(p1, off);
    }
    const int wv = tid >> 6, ln = tid & 63;
    if (ln == 0) { red[0][wv] = p0; red[1][wv] = p1; }
    __syncthreads();
    if (tid < 2) {
      float sum = b2[tid];
#pragma unroll
      for (int i = 0; i < 8; i++) sum += red[tid][i];
      out[b * 2 + tid] = sum;
    }
  }
}

// ---------------------------------------------------------------------------
extern "C" void kernel_launch(void* const* d_in, const int* in_sizes, int n_in,
                              void* d_out, int out_size, void* d_ws, size_t ws_size,
                              hipStream_t stream)
{
  const int*   x   = (const int*)d_in[0];
  const float* emb = (const float*)d_in[1];
  const float* W1  = (const float*)d_in[2];
  const float* b1  = (const float*)d_in[3];
  const float* W2  = (const float*)d_in[4];
  const float* b2  = (const float*)d_in[5];
  float* out = (float*)d_out;
  char* ws = (char*)d_ws;

  // ws layout: [0,256) flags | [8K, 8K+256K) h double-buffer | pooled | [512K, 512K+64M) px
  int*   flags  = (int*)ws;
  float* hbufs  = (float*)(ws + 8192);
  float* pooled = (float*)(ws + 8192 + (size_t)2 * BB * HIDD * 4);
  float* px     = (float*)(ws + (1 << 19));
  const size_t px_bytes = (size_t)BB * TT * HIDD * 4;
  const bool has_px = ws_size >= ((size_t)(1 << 19) + px_bytes);

  hipMemsetAsync(flags, 0, 256, stream);   // flags must be zero every launch (graph-replay safe)

  if (has_px) {
    dim3 g(TT * BB / 128, HIDD / 128);     // (256, 4)
    px_gemm<<<g, 256, 0, stream>>>(x, emb, W1, b1, px);
  }

  void* kargs[] = { (void*)&W1, (void*)&b1, (void*)&W2, (void*)&b2,
                    (void*)&emb, (void*)&x, (void*)&px, (void*)&hbufs,
                    (void*)&pooled, (void*)&flags, (void*)&out };
  hipError_t err;
  if (has_px)
    err = hipLaunchCooperativeKernel(reinterpret_cast<const void*>(&elman_rnn<true>),
                                     dim3(256), dim3(512), kargs, 0, stream);
  else
    err = hipLaunchCooperativeKernel(reinterpret_cast<const void*>(&elman_rnn<false>),
                                     dim3(256), dim3(512), kargs, 0, stream);
  if (err != hipSuccess) {
    // fallback: plain launch (256 wgs of 8 waves fit 1/CU -> co-resident in practice)
    if (has_px)
      elman_rnn<true><<<dim3(256), dim3(512), 0, stream>>>(W1, b1, W2, b2, emb, x, px, hbufs, pooled, flags, out);
    else
      elman_rnn<false><<<dim3(256), dim3(512), 0, stream>>>(W1, b1, W2, b2, emb, x, px, hbufs, pooled, flags, out);
  }
}

// Round 2
// 12326.625 us; speedup vs baseline: 2.0022x; 2.0022x over previous
//
#include <hip/hip_runtime.h>
#include <math.h>

#define TT  512   // timesteps
#define BB  64    // batch
#define EMBD 512
#define HIDD 512

// ---------------------------------------------------------------------------
// K1: px[m][j] = b1[j] + sum_k emb[x[m]][k] * W1[j][k]   (m = b*T+t, k<512)
// fp32 128x128x8 tile GEMM, 256 threads, 8x8 per thread.
// ---------------------------------------------------------------------------
__global__ __launch_bounds__(256) void px_gemm(
    const int* __restrict__ x, const float* __restrict__ emb,
    const float* __restrict__ W1, const float* __restrict__ b1,
    float* __restrict__ px)
{
  __shared__ float As[8][132];
  __shared__ float Bs[8][132];
  __shared__ int stok[128];
  const int tid = threadIdx.x;
  const int m0 = blockIdx.x * 128;
  const int j0 = blockIdx.y * 128;
  if (tid < 128) stok[tid] = x[m0 + tid];
  __syncthreads();
  const int lr = tid >> 1;          // 0..127
  const int lh = (tid & 1) * 4;     // 0 or 4
  const int ty = tid >> 4, tx = tid & 15;
  const size_t arow = (size_t)stok[lr] * EMBD;
  const float* brow = W1 + (size_t)(j0 + lr) * (2 * EMBD);

  float acc[8][8];
#pragma unroll
  for (int i = 0; i < 8; i++)
#pragma unroll
    for (int q = 0; q < 8; q++) acc[i][q] = 0.f;

  for (int k0 = 0; k0 < EMBD; k0 += 8) {
    float4 av = *(const float4*)(emb + arow + k0 + lh);
    float4 bv = *(const float4*)(brow + k0 + lh);
    __syncthreads();
    As[lh + 0][lr] = av.x; As[lh + 1][lr] = av.y; As[lh + 2][lr] = av.z; As[lh + 3][lr] = av.w;
    Bs[lh + 0][lr] = bv.x; Bs[lh + 1][lr] = bv.y; Bs[lh + 2][lr] = bv.z; Bs[lh + 3][lr] = bv.w;
    __syncthreads();
#pragma unroll
    for (int kk = 0; kk < 8; kk++) {
      float4 a0 = *(const float4*)&As[kk][ty * 8];
      float4 a1 = *(const float4*)&As[kk][ty * 8 + 4];
      float4 c0 = *(const float4*)&Bs[kk][tx * 8];
      float4 c1 = *(const float4*)&Bs[kk][tx * 8 + 4];
      float a[8] = {a0.x,a0.y,a0.z,a0.w,a1.x,a1.y,a1.z,a1.w};
      float bb[8] = {c0.x,c0.y,c0.z,c0.w,c1.x,c1.y,c1.z,c1.w};
#pragma unroll
      for (int i = 0; i < 8; i++)
#pragma unroll
        for (int q = 0; q < 8; q++)
          acc[i][q] = fmaf(a[i], bb[q], acc[i][q]);
    }
  }
  const float* bp = b1 + j0 + tx * 8;
  float bias0[8];
#pragma unroll
  for (int q = 0; q < 8; q++) bias0[q] = bp[q];
#pragma unroll
  for (int i = 0; i < 8; i++) {
    float o[8];
#pragma unroll
    for (int q = 0; q < 8; q++) o[q] = acc[i][q] + bias0[q];
    float* dst = px + (size_t)(m0 + ty * 8 + i) * HIDD + j0 + tx * 8;
    *(float4*)dst       = make_float4(o[0], o[1], o[2], o[3]);
    *(float4*)(dst + 4) = make_float4(o[4], o[5], o[6], o[7]);
  }
}

// ---------------------------------------------------------------------------
// K2: recurrence, ONE workgroup per batch (64 wgs x 1024 threads, 16 waves).
// Thread (j = tid&511, kc = tid>>9) holds W1h[j][kc*256..+256) in 256 VGPRs;
// the whole 1 MB W1h is register-resident per CU. Per step: broadcast
// ds_read of h, 256 FMAs/thread, 2-way LDS reduce, tanh, double-buffered h.
// Only 2 __syncthreads per step; no global sync, no atomics.
// ---------------------------------------------------------------------------
template<bool HAS_PX>
__global__ __launch_bounds__(1024, 4) void elman_rnn(
    const float* __restrict__ W1, const float* __restrict__ b1,
    const float* __restrict__ W2, const float* __restrict__ b2,
    const float* __restrict__ emb, const int* __restrict__ x,
    const float* __restrict__ px, float* __restrict__ out)
{
  const int b   = blockIdx.x;
  const int tid = threadIdx.x;
  const int j   = tid & 511;
  const int kc  = tid >> 9;        // 0 or 1: which half of k-space

  __shared__ float hl[2][HIDD];    // double-buffered hidden state
  __shared__ float parts[2][HIDD]; // k-half partial sums
  __shared__ float el[EMBD];       // fallback: staged embedding row
  __shared__ float red[2][8];

  // --- load recurrent weights into VGPRs (64 float4 = 256 regs) ---
  float4 w[64];
  {
    const float4* wp = (const float4*)(W1 + (size_t)j * (2 * EMBD) + EMBD + kc * 256);
#pragma unroll
    for (int i = 0; i < 64; i++) w[i] = wp[i];
  }

  float bias = 0.f;
  if (!HAS_PX && tid < HIDD) bias = b1[tid];

  if (tid < HIDD) hl[0][tid] = 0.f;
  float runmax = -INFINITY;
  __syncthreads();

  for (int t = 0; t < TT; t++) {
    const int cur = t & 1, nxt = cur ^ 1;

    // issue px load early; latency hidden under the dot product
    float pxv = 0.f;
    if constexpr (HAS_PX) {
      if (tid < HIDD) pxv = px[((size_t)b * TT + t) * HIDD + tid];
    } else {
      const int tk = x[b * TT + t];
      if (tid < EMBD) el[tid] = emb[(size_t)tk * EMBD + tid];
      __syncthreads();               // el visible before dot
    }

    // --- partial dot: 256 k-terms from hl[cur] (broadcast reads) ---
    float p[4] = {0.f, 0.f, 0.f, 0.f};
    const float4* h4 = (const float4*)(&hl[cur][kc * 256]);
#pragma unroll
    for (int i = 0; i < 64; i++) {
      float4 hv = h4[i];
      float4 wv = w[i];
      p[i & 3] = fmaf(wv.x, hv.x, p[i & 3]);
      p[i & 3] = fmaf(wv.y, hv.y, p[i & 3]);
      p[i & 3] = fmaf(wv.z, hv.z, p[i & 3]);
      p[i & 3] = fmaf(wv.w, hv.w, p[i & 3]);
    }
    if constexpr (!HAS_PX) {
      const float4* wx = (const float4*)(W1 + (size_t)j * (2 * EMBD) + kc * 256);
      const float4* e4 = (const float4*)(&el[kc * 256]);
#pragma unroll
      for (int i = 0; i < 64; i++) {
        float4 a = wx[i]; float4 e = e4[i];
        p[i & 3] = fmaf(a.x, e.x, p[i & 3]);
        p[i & 3] = fmaf(a.y, e.y, p[i & 3]);
        p[i & 3] = fmaf(a.z, e.z, p[i & 3]);
        p[i & 3] = fmaf(a.w, e.w, p[i & 3]);
      }
    }
    parts[kc][j] = (p[0] + p[1]) + (p[2] + p[3]);
    __syncthreads();

    // --- finalize: reduce halves, tanh, running max, publish h ---
    if (tid < HIDD) {
      float pre = parts[0][tid] + parts[1][tid] + pxv + bias;
      float hn = tanhf(pre);
      runmax = fmaxf(runmax, hn);
      hl[nxt][tid] = hn;
      if (t == TT - 1) out[2 * BB + (size_t)b * HIDD + tid] = hn;
    }
    __syncthreads();
  }

  // --- logits: out[b][o] = b2[o] + sum_j runmax[j] * W2[o][j] ---
  if (tid < HIDD) {
    float p0 = runmax * W2[tid];
    float p1 = runmax * W2[HIDD + tid];
#pragma unroll
    for (int off = 32; off; off >>= 1) {
      p0 += __shfl_down(p0, off);
      p1 += __shfl_down(p1, off);
    }
    const int wv = tid >> 6, ln = tid & 63;
    if (ln == 0) { red[0][wv] = p0; red[1][wv] = p1; }
  }
  __syncthreads();
  if (tid < 2) {
    float sum = b2[tid];
#pragma unroll
    for (int i = 0; i < 8; i++) sum += red[tid][i];
    out[b * 2 + tid] = sum;
  }
}

// ---------------------------------------------------------------------------
extern "C" void kernel_launch(void* const* d_in, const int* in_sizes, int n_in,
                              void* d_out, int out_size, void* d_ws, size_t ws_size,
                              hipStream_t stream)
{
  const int*   x   = (const int*)d_in[0];
  const float* emb = (const float*)d_in[1];
  const float* W1  = (const float*)d_in[2];
  const float* b1  = (const float*)d_in[3];
  const float* W2  = (const float*)d_in[4];
  const float* b2  = (const float*)d_in[5];
  float* out = (float*)d_out;

  float* px = (float*)d_ws;
  const size_t px_bytes = (size_t)BB * TT * HIDD * sizeof(float); // 64 MB
  const bool has_px = ws_size >= px_bytes;

  if (has_px) {
    dim3 g(TT * BB / 128, HIDD / 128);     // (256, 4)
    px_gemm<<<g, 256, 0, stream>>>(x, emb, W1, b1, px);
    elman_rnn<true><<<dim3(BB), dim3(1024), 0, stream>>>(
        W1, b1, W2, b2, emb, x, px, out);
  } else {
    elman_rnn<false><<<dim3(BB), dim3(1024), 0, stream>>>(
        W1, b1, W2, b2, emb, x, px, out);
  }
}

// Round 3
// 1082.094 us; speedup vs baseline: 22.8076x; 11.3915x over previous
//
#include <hip/hip_runtime.h>
#include <math.h>

#define TT   512
#define BB   64
#define EMBD 512
#define HIDD 512

typedef _Float16 half2v __attribute__((ext_vector_type(2)));

__device__ __forceinline__ float fdot2(unsigned a, unsigned b, float c) {
  half2v av = __builtin_bit_cast(half2v, a);
  half2v bv = __builtin_bit_cast(half2v, b);
#if __has_builtin(__builtin_amdgcn_fdot2)
  return __builtin_amdgcn_fdot2(av, bv, c, false);
#else
  return c + (float)av.x * (float)bv.x + (float)av.y * (float)bv.y;
#endif
}

// ---------------------------------------------------------------------------
// K0: repack W1h (fp32 [j][512..1024) of W1) into fp16, layout wp[sec][tid]:
// tid -> (j = tid&511, kc = tid>>9); section s holds k_local 8s..8s+7 as
// 4 dwords of packed (even,odd) fp16 pairs. 32 sections x 1024 x 16B = 512KB.
// All per-step reads in K2 become lane-coalesced or LDS-resident.
// ---------------------------------------------------------------------------
__global__ __launch_bounds__(256) void repack_w1h(
    const float* __restrict__ W1, uint4* __restrict__ wp)
{
  const int gid = blockIdx.x * 256 + threadIdx.x;   // 0..32767
  const int sec = gid >> 10;                        // 0..31
  const int tid = gid & 1023;
  const int j = tid & 511, kc = tid >> 9;
  const float* src = W1 + (size_t)j * (2 * EMBD) + EMBD + kc * 256 + 8 * sec;
  unsigned r[4];
#pragma unroll
  for (int c = 0; c < 4; c++) {
    half2v hv;
    hv.x = (_Float16)src[2 * c];
    hv.y = (_Float16)src[2 * c + 1];
    r[c] = __builtin_bit_cast(unsigned, hv);
  }
  uint4 u; u.x = r[0]; u.y = r[1]; u.z = r[2]; u.w = r[3];
  wp[gid] = u;
}

// ---------------------------------------------------------------------------
// K1: px[m][j] = b1[j] + sum_k emb[x[m]][k] * W1[j][k]  (fp32 tile GEMM)
// ---------------------------------------------------------------------------
__global__ __launch_bounds__(256) void px_gemm(
    const int* __restrict__ x, const float* __restrict__ emb,
    const float* __restrict__ W1, const float* __restrict__ b1,
    float* __restrict__ px)
{
  __shared__ float As[8][132];
  __shared__ float Bs[8][132];
  __shared__ int stok[128];
  const int tid = threadIdx.x;
  const int m0 = blockIdx.x * 128;
  const int j0 = blockIdx.y * 128;
  if (tid < 128) stok[tid] = x[m0 + tid];
  __syncthreads();
  const int lr = tid >> 1;
  const int lh = (tid & 1) * 4;
  const int ty = tid >> 4, tx = tid & 15;
  const size_t arow = (size_t)stok[lr] * EMBD;
  const float* brow = W1 + (size_t)(j0 + lr) * (2 * EMBD);

  float acc[8][8];
#pragma unroll
  for (int i = 0; i < 8; i++)
#pragma unroll
    for (int q = 0; q < 8; q++) acc[i][q] = 0.f;

  for (int k0 = 0; k0 < EMBD; k0 += 8) {
    float4 av = *(const float4*)(emb + arow + k0 + lh);
    float4 bv = *(const float4*)(brow + k0 + lh);
    __syncthreads();
    As[lh + 0][lr] = av.x; As[lh + 1][lr] = av.y; As[lh + 2][lr] = av.z; As[lh + 3][lr] = av.w;
    Bs[lh + 0][lr] = bv.x; Bs[lh + 1][lr] = bv.y; Bs[lh + 2][lr] = bv.z; Bs[lh + 3][lr] = bv.w;
    __syncthreads();
#pragma unroll
    for (int kk = 0; kk < 8; kk++) {
      float4 a0 = *(const float4*)&As[kk][ty * 8];
      float4 a1 = *(const float4*)&As[kk][ty * 8 + 4];
      float4 c0 = *(const float4*)&Bs[kk][tx * 8];
      float4 c1 = *(const float4*)&Bs[kk][tx * 8 + 4];
      float a[8] = {a0.x,a0.y,a0.z,a0.w,a1.x,a1.y,a1.z,a1.w};
      float bb[8] = {c0.x,c0.y,c0.z,c0.w,c1.x,c1.y,c1.z,c1.w};
#pragma unroll
      for (int i = 0; i < 8; i++)
#pragma unroll
        for (int q = 0; q < 8; q++)
          acc[i][q] = fmaf(a[i], bb[q], acc[i][q]);
    }
  }
  const float* bp = b1 + j0 + tx * 8;
  float bias0[8];
#pragma unroll
  for (int q = 0; q < 8; q++) bias0[q] = bp[q];
#pragma unroll
  for (int i = 0; i < 8; i++) {
    float o[8];
#pragma unroll
    for (int q = 0; q < 8; q++) o[q] = acc[i][q] + bias0[q];
    float* dst = px + (size_t)(m0 + ty * 8 + i) * HIDD + j0 + tx * 8;
    *(float4*)dst       = make_float4(o[0], o[1], o[2], o[3]);
    *(float4*)(dst + 4) = make_float4(o[4], o[5], o[6], o[7]);
  }
}

// ---------------------------------------------------------------------------
// K2: recurrence, one wg per batch (64 x 1024 thr). Thread (j=tid&511,
// kc=tid>>9) owns k-slice of 256 fp16 weights: sections 0..19 in VGPR
// (80 regs), 20..20+NL-1 in dynamic LDS, rest streamed from L2 per step.
// Dot via v_dot2_f32_f16 (fp32 accum); h packed to fp16 pairs each step.
// 2 barriers/step, no inter-wg traffic.
// ---------------------------------------------------------------------------
template<int NL>
__global__ __launch_bounds__(1024) void elman_fp16(
    const uint4* __restrict__ wp, const float* __restrict__ px,
    const float* __restrict__ W2, const float* __restrict__ b2,
    float* __restrict__ out)
{
  constexpr int NS = 12 - NL;               // streamed sections per step
  extern __shared__ uint4 wl[];             // NL*1024 uint4
  __shared__ __align__(16) unsigned h2[2][256];  // packed fp16 h, dbuf
  __shared__ float parts[2][HIDD];
  __shared__ float pl[HIDD];
  __shared__ float red[2][8];

  const int b   = blockIdx.x;
  const int tid = threadIdx.x;
  const int j   = tid & 511;
  const int kc  = tid >> 9;

  // prologue: register weights (coalesced), LDS weights
  uint4 wr[20];
#pragma unroll
  for (int i = 0; i < 20; i++) wr[i] = wp[(size_t)i * 1024 + tid];
#pragma unroll
  for (int i = 0; i < NL; i++) wl[i * 1024 + tid] = wp[(size_t)(20 + i) * 1024 + tid];
  if (tid < 256) h2[0][tid] = 0u;           // h0 = 0
  __syncthreads();

  float rm0 = -INFINITY, rm1 = -INFINITY;
  const float* pxb = px + (size_t)b * TT * HIDD;
  const uint4* wsrc = wp + (size_t)(20 + NL) * 1024 + tid;

  for (int t = 0; t < TT; t++) {
    const int cur = t & 1;

    // early issues: this step's px (finalize threads) + streamed weights
    float2 pxv = make_float2(0.f, 0.f);
    if (tid < 256) pxv = *(const float2*)(pxb + (size_t)t * HIDD + 2 * tid);
    uint4 sw[NS > 0 ? NS : 1];
#pragma unroll
    for (int i = 0; i < NS; i++) sw[i] = wsrc[(size_t)i * 1024];

    const uint4* h2u = reinterpret_cast<const uint4*>(&h2[cur][0]) + kc * 32;
    float p0 = 0.f, p1 = 0.f, p2 = 0.f, p3 = 0.f;
#pragma unroll
    for (int g = 0; g < 20; g++) {          // register weights
      uint4 hh = h2u[g];
      uint4 ww = wr[g];
      p0 = fdot2(ww.x, hh.x, p0);
      p1 = fdot2(ww.y, hh.y, p1);
      p2 = fdot2(ww.z, hh.z, p2);
      p3 = fdot2(ww.w, hh.w, p3);
    }
#pragma unroll
    for (int i = 0; i < NL; i++) {          // LDS weights
      uint4 hh = h2u[20 + i];
      uint4 ww = wl[i * 1024 + tid];
      p0 = fdot2(ww.x, hh.x, p0);
      p1 = fdot2(ww.y, hh.y, p1);
      p2 = fdot2(ww.z, hh.z, p2);
      p3 = fdot2(ww.w, hh.w, p3);
    }
#pragma unroll
    for (int i = 0; i < NS; i++) {          // streamed weights
      uint4 hh = h2u[20 + NL + i];
      uint4 ww = sw[i];
      p0 = fdot2(ww.x, hh.x, p0);
      p1 = fdot2(ww.y, hh.y, p1);
      p2 = fdot2(ww.z, hh.z, p2);
      p3 = fdot2(ww.w, hh.w, p3);
    }
    parts[kc][j] = (p0 + p1) + (p2 + p3);
    __syncthreads();

    if (tid < 256) {                        // finalize two j's per thread
      float2 pa = *(const float2*)&parts[0][2 * tid];
      float2 pb = *(const float2*)&parts[1][2 * tid];
      float h0 = tanhf(pa.x + pb.x + pxv.x);
      float h1 = tanhf(pa.y + pb.y + pxv.y);
      rm0 = fmaxf(rm0, h0);
      rm1 = fmaxf(rm1, h1);
      half2v hv; hv.x = (_Float16)h0; hv.y = (_Float16)h1;
      h2[cur ^ 1][tid] = __builtin_bit_cast(unsigned, hv);
      if (t == TT - 1)
        *(float2*)(out + 2 * BB + (size_t)b * HIDD + 2 * tid) = make_float2(h0, h1);
    }
    __syncthreads();
  }

  // pooled max -> logits
  if (tid < 256) { pl[2 * tid] = rm0; pl[2 * tid + 1] = rm1; }
  __syncthreads();
  if (tid < 512) {
    float pv = pl[tid];
    float q0 = pv * W2[tid];
    float q1 = pv * W2[HIDD + tid];
#pragma unroll
    for (int off = 32; off; off >>= 1) {
      q0 += __shfl_down(q0, off);
      q1 += __shfl_down(q1, off);
    }
    const int wv = tid >> 6, ln = tid & 63;
    if (ln == 0) { red[0][wv] = q0; red[1][wv] = q1; }
  }
  __syncthreads();
  if (tid < 2) {
    float s = b2[tid];
#pragma unroll
    for (int i = 0; i < 8; i++) s += red[tid][i];
    out[b * 2 + tid] = s;
  }
}

// ---------------------------------------------------------------------------
extern "C" void kernel_launch(void* const* d_in, const int* in_sizes, int n_in,
                              void* d_out, int out_size, void* d_ws, size_t ws_size,
                              hipStream_t stream)
{
  const int*   x   = (const int*)d_in[0];
  const float* emb = (const float*)d_in[1];
  const float* W1  = (const float*)d_in[2];
  const float* b1  = (const float*)d_in[3];
  const float* W2  = (const float*)d_in[4];
  const float* b2  = (const float*)d_in[5];
  float* out = (float*)d_out;
  char* ws = (char*)d_ws;

  uint4* wp = (uint4*)ws;                        // 512 KB repacked fp16 W1h
  float* px = (float*)(ws + (1 << 19));          // 64 MB
  const size_t need = (size_t)(1 << 19) + (size_t)BB * TT * HIDD * sizeof(float);
  if (ws_size < need) return;                    // verified >= in rounds 1-2

  repack_w1h<<<128, 256, 0, stream>>>(W1, wp);
  {
    dim3 g(TT * BB / 128, HIDD / 128);           // (256, 4)
    px_gemm<<<g, 256, 0, stream>>>(x, emb, W1, b1, px);
  }

  // primary: 9 weight-sections in dynamic LDS (147456 B) -> needs attribute
  const int dynNL = 9;
  const size_t dynBytes = (size_t)dynNL * 1024 * sizeof(uint4);
  hipError_t ae = hipFuncSetAttribute(
      reinterpret_cast<const void*>(&elman_fp16<9>),
      hipFuncAttributeMaxDynamicSharedMemorySize, (int)dynBytes);
  if (ae == hipSuccess) {
    elman_fp16<9><<<dim3(BB), dim3(1024), dynBytes, stream>>>(wp, px, W2, b2, out);
  } else {
    // fallback: no LDS weights, stream 12 sections/step (slower, correct)
    elman_fp16<0><<<dim3(BB), dim3(1024), 0, stream>>>(wp, px, W2, b2, out);
  }
}